// Round 2
// baseline (529.600 us; speedup 1.0000x reference)
//
#include <hip/hip_runtime.h>
#include <hip/hip_bf16.h>

#define NROWS 1048576
#define TM 128
#define NTHREADS 512

typedef __attribute__((ext_vector_type(8))) short short8;   // 8 x bf16 = 4 VGPR (MFMA A/B frag)
typedef __attribute__((ext_vector_type(4))) float f32x4;    // MFMA C/D frag

// round-to-nearest f32 -> bf16 (bit trick; tie-break bias negligible here)
__device__ __forceinline__ unsigned short f2bf(float f) {
    union { float f; unsigned int u; } v; v.f = f;
    return (unsigned short)((v.u + 0x8000u) >> 16);
}

// XOR swizzles (Guideline 4): spread rows of row-major bf16 tiles across banks.
// rowBytes=64 tiles can only swizzle 2 bits; rowBytes=256 gets the full 3.
__device__ __forceinline__ int swz64(int row, int kByte) {
    return row * 64 + (kByte ^ ((row & 3) << 4));
}
__device__ __forceinline__ int swz256(int row, int kByte) {
    return row * 256 + (kByte ^ ((row & 7) << 4));
}

__global__ __launch_bounds__(NTHREADS, 2)
void coupling_fwd(const float* __restrict__ x,  const float* __restrict__ ctx,
                  const float* __restrict__ W1, const float* __restrict__ b1,
                  const float* __restrict__ W2, const float* __restrict__ b2,
                  const float* __restrict__ W3, const float* __restrict__ b3,
                  float* __restrict__ y, float* __restrict__ ld) {
    // weights transposed: sW*[n][k] (B-operand wants contiguous k per output col n)
    __shared__ alignas(16) unsigned short sW1[128 * 32];   // 8 KB  (K padded 24->32)
    __shared__ alignas(16) unsigned short sW2[128 * 128];  // 32 KB
    __shared__ alignas(16) unsigned short sW3[32 * 128];   // 8 KB
    __shared__ alignas(16) unsigned short sA1[TM * 32];    // 8 KB  layer-1 input (bf16)
    __shared__ alignas(16) unsigned short sH[TM * 128];    // 32 KB hidden acts (bf16)
    __shared__ alignas(16) float sX[TM * 36];              // 18 KB raw x (stride 36 = 16B-aligned rows, bank-spread)
    __shared__ alignas(16) float sB[288];                  // b1 | b2 | b3

    const int tid   = threadIdx.x;
    const int bRow0 = blockIdx.x * TM;

    // ---------------- stage x / ctx -> sX + sA1 (net_in, bf16, swizzled) ----------------
    if (tid < 256) {
        int row = tid >> 1, hf = tid & 1;           // each thread: 16 floats of one x row
        const float4* gx = (const float4*)(x + (size_t)(bRow0 + row) * 32 + hf * 16);
        float4 v0 = gx[0], v1 = gx[1], v2 = gx[2], v3 = gx[3];
        float4* px = (float4*)(sX + row * 36 + hf * 16);
        px[0] = v0; px[1] = v1; px[2] = v2; px[3] = v3;
        short8 fr;                                   // even-index (masked) elems -> k = hf*8 .. +7
        fr[0] = (short)f2bf(v0.x); fr[1] = (short)f2bf(v0.z);
        fr[2] = (short)f2bf(v1.x); fr[3] = (short)f2bf(v1.z);
        fr[4] = (short)f2bf(v2.x); fr[5] = (short)f2bf(v2.z);
        fr[6] = (short)f2bf(v3.x); fr[7] = (short)f2bf(v3.z);
        *(short8*)((char*)sA1 + swz64(row, hf * 16)) = fr;
    } else if (tid < 384) {
        int row = tid - 256;                         // context -> k = 16..23
        const float4* gc = (const float4*)(ctx + (size_t)(bRow0 + row) * 8);
        float4 c0 = gc[0], c1 = gc[1];
        short8 fr;
        fr[0] = (short)f2bf(c0.x); fr[1] = (short)f2bf(c0.y);
        fr[2] = (short)f2bf(c0.z); fr[3] = (short)f2bf(c0.w);
        fr[4] = (short)f2bf(c1.x); fr[5] = (short)f2bf(c1.y);
        fr[6] = (short)f2bf(c1.z); fr[7] = (short)f2bf(c1.w);
        *(short8*)((char*)sA1 + swz64(row, 32)) = fr;
    } else {
        int row = tid - 384;                         // K-pad zeros, k = 24..31
        short8 z = {};
        *(short8*)((char*)sA1 + swz64(row, 48)) = z;
    }

    // ---------------- stage weights: global f32 (L2-resident) -> transposed bf16 LDS ----------------
    // W2 (128k x 128n): 4096 float4 tasks, coalesced reads, scalar transposed writes
#pragma unroll
    for (int it = 0; it < 8; ++it) {
        int i = tid + it * NTHREADS;
        int k = i >> 5, n0 = (i & 31) * 4;
        float4 w = *(const float4*)(W2 + k * 128 + n0);
        *(unsigned short*)((char*)sW2 + swz256(n0 + 0, 2 * k)) = f2bf(w.x);
        *(unsigned short*)((char*)sW2 + swz256(n0 + 1, 2 * k)) = f2bf(w.y);
        *(unsigned short*)((char*)sW2 + swz256(n0 + 2, 2 * k)) = f2bf(w.z);
        *(unsigned short*)((char*)sW2 + swz256(n0 + 3, 2 * k)) = f2bf(w.w);
    }
    // W1 (24k x 128n)
    for (int i = tid; i < 768; i += NTHREADS) {
        int k = i >> 5, n0 = (i & 31) * 4;
        float4 w = *(const float4*)(W1 + k * 128 + n0);
        *(unsigned short*)((char*)sW1 + swz64(n0 + 0, 2 * k)) = f2bf(w.x);
        *(unsigned short*)((char*)sW1 + swz64(n0 + 1, 2 * k)) = f2bf(w.y);
        *(unsigned short*)((char*)sW1 + swz64(n0 + 2, 2 * k)) = f2bf(w.z);
        *(unsigned short*)((char*)sW1 + swz64(n0 + 3, 2 * k)) = f2bf(w.w);
    }
    if (tid < 128) {                                 // zero k = 24..31 of W1t
        short8 z = {};
        *(short8*)((char*)sW1 + swz64(tid, 48)) = z;
    }
    // W3 (128k x 32n)
    for (int i = tid; i < 1024; i += NTHREADS) {
        int k = i >> 3, n0 = (i & 7) * 4;
        float4 w = *(const float4*)(W3 + k * 32 + n0);
        *(unsigned short*)((char*)sW3 + swz256(n0 + 0, 2 * k)) = f2bf(w.x);
        *(unsigned short*)((char*)sW3 + swz256(n0 + 1, 2 * k)) = f2bf(w.y);
        *(unsigned short*)((char*)sW3 + swz256(n0 + 2, 2 * k)) = f2bf(w.z);
        *(unsigned short*)((char*)sW3 + swz256(n0 + 3, 2 * k)) = f2bf(w.w);
    }
    if (tid < 288) {
        sB[tid] = tid < 128 ? b1[tid] : (tid < 256 ? b2[tid - 128] : b3[tid - 256]);
    }
    __syncthreads();

    // ---------------- per-wave MFMA: wave owns a 16-row M-tile ----------------
    const int lane = tid & 63;
    const int lr   = lane & 15;   // A-row / B-col / D-col
    const int lc   = lane >> 4;   // k-chunk selector; D rows = lc*4 + reg
    const int rb   = (tid >> 6) * 16;

    // ---- layer 1: net_in(16x32) @ W1t -> h1(16x128) ----
    short8 a1 = *(const short8*)((const char*)sA1 + swz64(rb + lr, lc * 16));
    f32x4 acc1[8];
#pragma unroll
    for (int nt = 0; nt < 8; ++nt) {
        short8 b = *(const short8*)((const char*)sW1 + swz64(nt * 16 + lr, lc * 16));
        acc1[nt] = __builtin_amdgcn_mfma_f32_16x16x32_bf16(a1, b, (f32x4){0.f, 0.f, 0.f, 0.f}, 0, 0, 0);
    }
#pragma unroll
    for (int nt = 0; nt < 8; ++nt) {
        float bias = sB[nt * 16 + lr];
#pragma unroll
        for (int r = 0; r < 4; ++r) {
            int row = rb + lc * 4 + r;
            float v = acc1[nt][r] + bias;
            v = v > 0.f ? v : 0.f;
            *(unsigned short*)((char*)sH + swz256(row, (nt * 16 + lr) * 2)) = f2bf(v);
        }
    }
    __syncthreads();

    // ---- layer 2: h1 @ W2t -> h2 (K = 128, 4 K-steps) ----
    short8 a2[4];
#pragma unroll
    for (int ks = 0; ks < 4; ++ks)
        a2[ks] = *(const short8*)((const char*)sH + swz256(rb + lr, ks * 64 + lc * 16));
    f32x4 acc2[8];
#pragma unroll
    for (int nt = 0; nt < 8; ++nt) acc2[nt] = (f32x4){0.f, 0.f, 0.f, 0.f};
#pragma unroll
    for (int ks = 0; ks < 4; ++ks) {
#pragma unroll
        for (int nt = 0; nt < 8; ++nt) {
            short8 b = *(const short8*)((const char*)sW2 + swz256(nt * 16 + lr, ks * 64 + lc * 16));
            acc2[nt] = __builtin_amdgcn_mfma_f32_16x16x32_bf16(a2[ks], b, acc2[nt], 0, 0, 0);
        }
    }
    __syncthreads();   // waves only touch their own rows; barrier is cheap insurance
#pragma unroll
    for (int nt = 0; nt < 8; ++nt) {
        float bias = sB[128 + nt * 16 + lr];
#pragma unroll
        for (int r = 0; r < 4; ++r) {
            int row = rb + lc * 4 + r;
            float v = acc2[nt][r] + bias;
            v = v > 0.f ? v : 0.f;
            *(unsigned short*)((char*)sH + swz256(row, (nt * 16 + lr) * 2)) = f2bf(v);
        }
    }
    __syncthreads();

    // ---- layer 3: h2 @ W3t -> st(16x32); cols 0..15 = s, 16..31 = t ----
    short8 a3[4];
#pragma unroll
    for (int ks = 0; ks < 4; ++ks)
        a3[ks] = *(const short8*)((const char*)sH + swz256(rb + lr, ks * 64 + lc * 16));
    f32x4 s0 = (f32x4){0.f, 0.f, 0.f, 0.f};
    f32x4 s1 = (f32x4){0.f, 0.f, 0.f, 0.f};
#pragma unroll
    for (int ks = 0; ks < 4; ++ks) {
        short8 bs = *(const short8*)((const char*)sW3 + swz256(lr,      ks * 64 + lc * 16));
        short8 bt = *(const short8*)((const char*)sW3 + swz256(16 + lr, ks * 64 + lc * 16));
        s0 = __builtin_amdgcn_mfma_f32_16x16x32_bf16(a3[ks], bs, s0, 0, 0, 0);
        s1 = __builtin_amdgcn_mfma_f32_16x16x32_bf16(a3[ks], bt, s1, 0, 0, 0);
    }

    // ---- epilogue: s=tanh, y_even = x_even, y_odd = x_odd*e^s + t, log_det = sum(s) ----
    float bs3 = sB[256 + lr];
    float bt3 = sB[256 + 16 + lr];
#pragma unroll
    for (int r = 0; r < 4; ++r) {
        int row = rb + lc * 4 + r;                    // block-local row; this lane's col pair = (2*lr, 2*lr+1)
        float sv = tanhf(s0[r] + bs3);
        float tv = s1[r] + bt3;
        float2 xv = *(const float2*)(sX + row * 36 + 2 * lr);
        float es = __expf(sv);
        float2 o;
        o.x = xv.x;                                   // even index: passthrough
        o.y = xv.y * es + tv;                         // odd index: affine
        *(float2*)(y + (size_t)(bRow0 + row) * 32 + 2 * lr) = o;
        // reduce s over the 16 cols held by this 16-lane group
        float ss = sv;
        ss += __shfl_xor(ss, 1, 16);
        ss += __shfl_xor(ss, 2, 16);
        ss += __shfl_xor(ss, 4, 16);
        ss += __shfl_xor(ss, 8, 16);
        if (lr == 0) ld[bRow0 + row] = ss;
    }
}

extern "C" void kernel_launch(void* const* d_in, const int* in_sizes, int n_in,
                              void* d_out, int out_size, void* d_ws, size_t ws_size,
                              hipStream_t stream) {
    const float* x  = (const float*)d_in[0];
    const float* c  = (const float*)d_in[1];
    const float* W1 = (const float*)d_in[2];
    const float* b1 = (const float*)d_in[3];
    const float* W2 = (const float*)d_in[4];
    const float* b2 = (const float*)d_in[5];
    const float* W3 = (const float*)d_in[6];
    const float* b3 = (const float*)d_in[7];
    float* y  = (float*)d_out;
    float* ld = y + (size_t)NROWS * 32;
    coupling_fwd<<<dim3(NROWS / TM), dim3(NTHREADS), 0, stream>>>(x, c, W1, b1, W2, b2, W3, b3, y, ld);
}

// Round 4
// 272.298 us; speedup vs baseline: 1.9449x; 1.9449x over previous
//
#include <hip/hip_runtime.h>
#include <hip/hip_bf16.h>

#define NROWS 1048576
#define TM 128            // rows per block (4 waves x 32 rows)
#define NTHREADS 256

// ---- weight image layout in d_ws / LDS (bf16, pre-swizzled, pre-permuted) ----
#define OFF_W1 0          // 128 rows(p1) x 64B  (K=32 incl bias@k-slot, zeros pad)
#define OFF_W2 8192       // 128 rows(p2) x 256B
#define OFF_W3 40960      // 32 rows(n3)  x 256B
#define OFF_B2 49152      // 128 f32 (permuted b2)
#define OFF_B3 49664      // 32 f32
#define IMG_BYTES 49792
#define IMG_PAD 50176     // 49 x 1KB chunks

typedef __attribute__((ext_vector_type(8))) short short8;   // MFMA A/B frag (8 bf16)
typedef __attribute__((ext_vector_type(4))) float f32x4;    // MFMA C/D frag

union U8 { unsigned int u[4]; short8 s8; };

__device__ __forceinline__ unsigned short f2bf(float f) {
    union { float f; unsigned int u; } v; v.f = f;
    return (unsigned short)((v.u + 0x8000u) >> 16);
}
__device__ __forceinline__ unsigned int pack2bf(float lo, float hi) {
    return (unsigned int)f2bf(lo) | ((unsigned int)f2bf(hi) << 16);
}
// RNE pack for activations (compiler emits v_cvt_pk_bf16_f32)
__device__ __forceinline__ unsigned int pkrn(float lo, float hi) {
    float2 t; t.x = lo; t.y = hi;
    __hip_bfloat162 h = __float22bfloat162_rn(t);
    union { __hip_bfloat162 b; unsigned int u; } cv; cv.b = h; return cv.u;
}
// sigma: lane-repack map, B-frag k-position -> previous layer's D-position.
// Bit rotation (p6..p0) -> (p2 p6 p5 p4 p3 p1 p0); 5-cycle, NOT an involution.
__device__ __forceinline__ int sigma(int p) {
    int ks = (p >> 5) & 3, lcp = (p >> 3) & 3, b = (p >> 2) & 1, r = p & 3;
    return (b * 4 + ks) * 16 + lcp * 4 + r;
}
// k-axis of W2/W3 needs tau(sigma(q)) = sigma(sigma(q))  [R3 bugfix: was sigma(q)]
__device__ __forceinline__ int sigma2(int p) { return sigma(sigma(p)); }

__device__ __forceinline__ float fast_tanh(float v) {
    float a = fabsf(v);
    float e = __expf(2.f * a);            // inf-safe: e->inf => r->1
    float r = 1.f - 2.f / (e + 1.f);
    return copysignf(r, v);
}

// ---------------- precompute: weights -> permuted+swizzled bf16 image ----------------
// W1 k-permutation: virtual q = 8*lcq + j holds:
//   j<4 : masked feature 4*lcq+j  (= W1 row 4*lcq+j)
//   j=4,5: ctx feature 2*lcq+(j-4) (= W1 row 16+2*lcq+(j-4))
//   j=6 : bias slot (weight=b1) iff lcq==0, else 0   (input supplies 1.0 at lc==0)
//   j=7 : 0
__device__ __forceinline__ float w1val(const float* W1, const float* b1, int o, int q) {
    int lcq = q >> 3, j = q & 7;
    if (j < 4) return W1[(lcq * 4 + j) * 128 + o];
    if (j < 6) return W1[(16 + lcq * 2 + (j - 4)) * 128 + o];
    if (j == 6) return (lcq == 0) ? b1[o] : 0.f;
    return 0.f;
}

__global__ void build_image(const float* __restrict__ W1, const float* __restrict__ b1,
                            const float* __restrict__ W2, const float* __restrict__ b2,
                            const float* __restrict__ W3, const float* __restrict__ b3,
                            unsigned char* __restrict__ ws) {
    int g = blockIdx.x * NTHREADS + threadIdx.x;
    if (g < 2048) {                                   // W1: 128 p1 x 16 u32
        int p1 = g >> 4, vp = g & 15, q = vp * 2;
        int o = sigma(p1);                            // row-axis: tau = sigma
        unsigned int u = pack2bf(w1val(W1, b1, o, q), w1val(W1, b1, o, q + 1));
        *(unsigned int*)(ws + OFF_W1 + p1 * 64 + ((vp * 4) ^ ((p1 & 3) << 4))) = u;
    } else if (g < 10240) {                           // W2: 128 p2 x 64 u32
        int t = g - 2048, p2 = t >> 6, vp = t & 63;
        int o2 = sigma(p2);                           // row-axis: tau2 = sigma
        int oa = sigma2(vp * 2), ob = sigma2(vp * 2 + 1);   // k-axis: sigma^2
        unsigned int u = pack2bf(W2[oa * 128 + o2], W2[ob * 128 + o2]);
        *(unsigned int*)(ws + OFF_W2 + p2 * 256 + ((vp * 4) ^ ((p2 & 7) << 4))) = u;
    } else if (g < 12288) {                           // W3: 32 n3 x 64 u32
        int t = g - 10240, n3 = t >> 6, vp = t & 63;
        int oa = sigma2(vp * 2), ob = sigma2(vp * 2 + 1);   // k-axis: sigma^2
        unsigned int u = pack2bf(W3[oa * 32 + n3], W3[ob * 32 + n3]);
        *(unsigned int*)(ws + OFF_W3 + n3 * 256 + ((vp * 4) ^ ((n3 & 7) << 4))) = u;
    } else if (g < 12416) {                           // b2 (permuted by tau2)
        int p2 = g - 12288;
        *(float*)(ws + OFF_B2 + p2 * 4) = b2[sigma(p2)];
    } else if (g < 12448) {                           // b3 (unpermuted)
        int n3 = g - 12416;
        *(float*)(ws + OFF_B3 + n3 * 4) = b3[n3];
    }
}

// ---------------- main kernel: 4 waves x 32 rows, all-register dataflow ----------------
__global__ __launch_bounds__(NTHREADS, 3)
void coupling_fwd(const float* __restrict__ x, const float* __restrict__ ctx,
                  const unsigned char* __restrict__ wsimg,
                  float* __restrict__ y, float* __restrict__ ld) {
    __shared__ alignas(16) unsigned char img[IMG_PAD];
    const int tid = threadIdx.x, wave = tid >> 6, lane = tid & 63;
    const int lr = lane & 15, lc = lane >> 4;
    const int bRow0 = blockIdx.x * TM;

    // bulk-load pre-swizzled weight image -> LDS (linear dest: no conflicts, no VALU)
    for (int c = wave; c < 49; c += 4) {
        __builtin_amdgcn_global_load_lds(
            (const __attribute__((address_space(1))) void*)(wsimg + c * 1024 + lane * 16),
            (__attribute__((address_space(3))) void*)(img + c * 1024), 16, 0, 0);
    }

    // x/ctx -> registers (x read ONCE; f32 kept for epilogue). Lane owns cols [8lc,8lc+8).
    const int row0 = bRow0 + wave * 32 + lr;          // row-set 0; set 1 = +16
    const float* xp = x + (size_t)row0 * 32 + lc * 8;
    float4 xa00 = *(const float4*)xp,        xa01 = *(const float4*)(xp + 4);
    float4 xa10 = *(const float4*)(xp + 512), xa11 = *(const float4*)(xp + 516);
    float2 cx0 = *(const float2*)(ctx + (size_t)row0 * 8 + lc * 2);
    float2 cx1 = *(const float2*)(ctx + (size_t)(row0 + 16) * 8 + lc * 2);

    // layer-1 B fragments (virtual k-order; bias-ONE at lc==0 slot j=6)
    U8 B1[2];
    B1[0].u[0] = pkrn(xa00.x, xa00.z); B1[0].u[1] = pkrn(xa01.x, xa01.z);
    B1[0].u[2] = pkrn(cx0.x, cx0.y);   B1[0].u[3] = (lc == 0) ? 0x00003f80u : 0u;
    B1[1].u[0] = pkrn(xa10.x, xa10.z); B1[1].u[1] = pkrn(xa11.x, xa11.z);
    B1[1].u[2] = pkrn(cx1.x, cx1.y);   B1[1].u[3] = (lc == 0) ? 0x00003f80u : 0u;

    __syncthreads();                                   // image resident

    const int xr1 = (lr & 3) << 4;                     // W1 row-XOR ((row&3)<<4, row%16==lr)
    const int xr2 = (lr & 7) << 4;                     // W2/W3 row-XOR

    // ---- layer 1: D1[p1] = W1img . B1 ----
    f32x4 acc1[2][8];
#pragma unroll
    for (int mt = 0; mt < 8; ++mt) {
        short8 A = *(const short8*)(img + OFF_W1 + (mt * 16 + lr) * 64 + ((lc * 16) ^ xr1));
        acc1[0][mt] = __builtin_amdgcn_mfma_f32_16x16x32_bf16(A, B1[0].s8, (f32x4){0.f,0.f,0.f,0.f}, 0, 0, 0);
        acc1[1][mt] = __builtin_amdgcn_mfma_f32_16x16x32_bf16(A, B1[1].s8, (f32x4){0.f,0.f,0.f,0.f}, 0, 0, 0);
    }
    // relu + pack: D-frag registers ARE next layer's B-frag (hidden-perm trick)
    U8 B2[2][4];
#pragma unroll
    for (int s = 0; s < 2; ++s)
#pragma unroll
        for (int ks = 0; ks < 4; ++ks) {
            B2[s][ks].u[0] = pkrn(fmaxf(acc1[s][ks][0], 0.f),     fmaxf(acc1[s][ks][1], 0.f));
            B2[s][ks].u[1] = pkrn(fmaxf(acc1[s][ks][2], 0.f),     fmaxf(acc1[s][ks][3], 0.f));
            B2[s][ks].u[2] = pkrn(fmaxf(acc1[s][4 + ks][0], 0.f), fmaxf(acc1[s][4 + ks][1], 0.f));
            B2[s][ks].u[3] = pkrn(fmaxf(acc1[s][4 + ks][2], 0.f), fmaxf(acc1[s][4 + ks][3], 0.f));
        }

    // ---- layer 2: K=128, bias via C-init ----
    f32x4 acc2[2][8];
#pragma unroll
    for (int mt = 0; mt < 8; ++mt) {
        f32x4 bb = *(const f32x4*)(img + OFF_B2 + (mt * 16 + lc * 4) * 4);
        acc2[0][mt] = bb; acc2[1][mt] = bb;
    }
#pragma unroll
    for (int ks = 0; ks < 4; ++ks)
#pragma unroll
        for (int mt = 0; mt < 8; ++mt) {
            short8 A = *(const short8*)(img + OFF_W2 + (mt * 16 + lr) * 256 + ((ks * 64 + lc * 16) ^ xr2));
            acc2[0][mt] = __builtin_amdgcn_mfma_f32_16x16x32_bf16(A, B2[0][ks].s8, acc2[0][mt], 0, 0, 0);
            acc2[1][mt] = __builtin_amdgcn_mfma_f32_16x16x32_bf16(A, B2[1][ks].s8, acc2[1][mt], 0, 0, 0);
        }
    U8 B3[2][4];
#pragma unroll
    for (int s = 0; s < 2; ++s)
#pragma unroll
        for (int ks = 0; ks < 4; ++ks) {
            B3[s][ks].u[0] = pkrn(fmaxf(acc2[s][ks][0], 0.f),     fmaxf(acc2[s][ks][1], 0.f));
            B3[s][ks].u[1] = pkrn(fmaxf(acc2[s][ks][2], 0.f),     fmaxf(acc2[s][ks][3], 0.f));
            B3[s][ks].u[2] = pkrn(fmaxf(acc2[s][4 + ks][0], 0.f), fmaxf(acc2[s][4 + ks][1], 0.f));
            B3[s][ks].u[3] = pkrn(fmaxf(acc2[s][4 + ks][2], 0.f), fmaxf(acc2[s][4 + ks][3], 0.f));
        }

    // ---- layer 3: st (s = virtual rows 0..15 of mt=0, t = mt=1), bias via C-init ----
    f32x4 acc3[2][2];
#pragma unroll
    for (int mt = 0; mt < 2; ++mt) {
        f32x4 bb = *(const f32x4*)(img + OFF_B3 + (mt * 16 + lc * 4) * 4);
        acc3[0][mt] = bb; acc3[1][mt] = bb;
    }
#pragma unroll
    for (int ks = 0; ks < 4; ++ks)
#pragma unroll
        for (int mt = 0; mt < 2; ++mt) {
            short8 A = *(const short8*)(img + OFF_W3 + (mt * 16 + lr) * 256 + ((ks * 64 + lc * 16) ^ xr2));
            acc3[0][mt] = __builtin_amdgcn_mfma_f32_16x16x32_bf16(A, B3[0][ks].s8, acc3[0][mt], 0, 0, 0);
            acc3[1][mt] = __builtin_amdgcn_mfma_f32_16x16x32_bf16(A, B3[1][ks].s8, acc3[1][mt], 0, 0, 0);
        }

    // ---- epilogue: lane owns rows row0(+16), dims i = lc*4+r -> x cols 8lc+2r(+1) ----
#pragma unroll
    for (int s = 0; s < 2; ++s) {
        const int row = row0 + s * 16;
        float xv[8];
        if (s == 0) {
            xv[0]=xa00.x; xv[1]=xa00.y; xv[2]=xa00.z; xv[3]=xa00.w;
            xv[4]=xa01.x; xv[5]=xa01.y; xv[6]=xa01.z; xv[7]=xa01.w;
        } else {
            xv[0]=xa10.x; xv[1]=xa10.y; xv[2]=xa10.z; xv[3]=xa10.w;
            xv[4]=xa11.x; xv[5]=xa11.y; xv[6]=xa11.z; xv[7]=xa11.w;
        }
        float sv[4], tv[4];
#pragma unroll
        for (int r = 0; r < 4; ++r) {
            sv[r] = fast_tanh(acc3[s][0][r]);
            tv[r] = acc3[s][1][r];
        }
        float4 o0, o1;
        o0.x = xv[0]; o0.y = xv[1] * __expf(sv[0]) + tv[0];
        o0.z = xv[2]; o0.w = xv[3] * __expf(sv[1]) + tv[1];
        o1.x = xv[4]; o1.y = xv[5] * __expf(sv[2]) + tv[2];
        o1.z = xv[6]; o1.w = xv[7] * __expf(sv[3]) + tv[3];
        float* yp = y + (size_t)row * 32 + lc * 8;
        *(float4*)yp = o0; *(float4*)(yp + 4) = o1;

        float ss = sv[0] + sv[1] + sv[2] + sv[3];
        ss += __shfl_xor(ss, 16, 64);
        ss += __shfl_xor(ss, 32, 64);
        if (lc == 0) ld[row] = ss;
    }
}

extern "C" void kernel_launch(void* const* d_in, const int* in_sizes, int n_in,
                              void* d_out, int out_size, void* d_ws, size_t ws_size,
                              hipStream_t stream) {
    const float* x  = (const float*)d_in[0];
    const float* c  = (const float*)d_in[1];
    const float* W1 = (const float*)d_in[2];
    const float* b1 = (const float*)d_in[3];
    const float* W2 = (const float*)d_in[4];
    const float* b2 = (const float*)d_in[5];
    const float* W3 = (const float*)d_in[6];
    const float* b3 = (const float*)d_in[7];
    unsigned char* ws = (unsigned char*)d_ws;
    float* y  = (float*)d_out;
    float* ld = y + (size_t)NROWS * 32;

    build_image<<<dim3(49), dim3(NTHREADS), 0, stream>>>(W1, b1, W2, b2, W3, b3, ws);
    coupling_fwd<<<dim3(NROWS / TM), dim3(NTHREADS), 0, stream>>>(x, c, ws, y, ld);
}